// Round 9
// baseline (745.645 us; speedup 1.0000x reference)
//
#include <hip/hip_runtime.h>
#include <hip/hip_bf16.h>

typedef short s16x8 __attribute__((ext_vector_type(8)));
typedef float f32x4 __attribute__((ext_vector_type(4)));

#define MFMA_BF16(a,b,c) __builtin_amdgcn_mfma_f32_16x16x32_bf16((a),(b),(c),0,0,0)

static __device__ __forceinline__ unsigned short f2bf(float f){
  unsigned u = __builtin_bit_cast(unsigned, f);
  u += 0x7fffu + ((u >> 16) & 1u);          // RNE
  return (unsigned short)(u >> 16);
}
static __device__ __forceinline__ float bf2f(unsigned short h){
  unsigned u = ((unsigned)h) << 16;
  return __builtin_bit_cast(float, u);
}
// XOR swizzle on 16B chunks. lw = row width in shorts.
static __device__ __forceinline__ int swzi(int row, int col, int lw){
  const int chunk = (col >> 3) ^ ((row ^ (row >> 3)) & 7);
  return row*lw + (chunk << 3) + (col & 7);
}

// ---------------- kernel 0: W transpose + hi/lo split ------------------------
__global__ __launch_bounds__(128) void k0_wt(const float* __restrict__ W,
                                             unsigned short* __restrict__ wtH,
                                             unsigned short* __restrict__ wtL){
  const int n = blockIdx.x;       // 0..255 output col
  const int c = threadIdx.x;      // 0..127 input ch
  const float v = W[(size_t)c*256 + n];
  const unsigned short h = f2bf(v);
  wtH[n*128 + c] = h;
  wtL[n*128 + c] = f2bf(v - bf2f(h));
}

// ---------------- kernel 1: qkv = x @ W (split-bf16) -------------------------
__global__ __launch_bounds__(512,2) void k1_qkv(const float* __restrict__ x,
    const unsigned short* __restrict__ wtH, const unsigned short* __restrict__ wtL,
    unsigned short* __restrict__ qh, unsigned short* __restrict__ ql,
    unsigned short* __restrict__ kh, unsigned short* __restrict__ kl,
    unsigned short* __restrict__ vT){
  __shared__ unsigned short xh[16384], xl[16384];   // 64 KB
  const int t = threadIdx.x;
  const int lane = t & 63, wid = t >> 6;
  const int li = lane & 15, g = lane >> 4;
  const int m0 = blockIdx.x * 128;
  const int wm = wid >> 2, wn = wid & 3;

  // stage x tile (128 rows x 128 ch), split hi/lo, swizzled
  {
    const int row = t >> 2, cb = (t & 3) * 32;
    const float* src = x + (size_t)(m0 + row)*128 + cb;
    #pragma unroll
    for (int gg = 0; gg < 4; ++gg){
      const float4 v0 = ((const float4*)src)[2*gg];
      const float4 v1 = ((const float4*)src)[2*gg + 1];
      const float vv[8] = {v0.x,v0.y,v0.z,v0.w,v1.x,v1.y,v1.z,v1.w};
      s16x8 h, l;
      #pragma unroll
      for (int j = 0; j < 8; ++j){
        const unsigned short hb = f2bf(vv[j]);
        h[j] = (short)hb;
        l[j] = (short)f2bf(vv[j] - bf2f(hb));
      }
      const int idx = swzi(row, cb + 8*gg, 128);
      *(s16x8*)&xh[idx] = h;
      *(s16x8*)&xl[idx] = l;
    }
  }
  __syncthreads();

  // ---- half 0: q,k (operand-swapped: D[m=outch][n=pos]) ----
  {
    f32x4 acc[4][2] = {};
    #pragma unroll
    for (int ks = 0; ks < 4; ++ks){
      const int col = ks*32 + g*8;
      s16x8 ah[4], al[4];
      #pragma unroll
      for (int mi = 0; mi < 4; ++mi){
        const int idx = swzi(wm*64 + mi*16 + li, col, 128);
        ah[mi] = *(const s16x8*)&xh[idx];
        al[mi] = *(const s16x8*)&xl[idx];
      }
      #pragma unroll
      for (int ni = 0; ni < 2; ++ni){
        const size_t boff = (size_t)(wn*32 + ni*16 + li)*128 + col;
        const s16x8 bh = *(const s16x8*)(wtH + boff);
        const s16x8 bl = *(const s16x8*)(wtL + boff);
        #pragma unroll
        for (int mi = 0; mi < 4; ++mi){
          acc[mi][ni] = MFMA_BF16(bh, ah[mi], acc[mi][ni]);   // A=W, B=x
          acc[mi][ni] = MFMA_BF16(bh, al[mi], acc[mi][ni]);
          acc[mi][ni] = MFMA_BF16(bl, ah[mi], acc[mi][ni]);
        }
      }
    }
    #pragma unroll
    for (int mi = 0; mi < 4; ++mi)
      #pragma unroll
      for (int ni = 0; ni < 2; ++ni){
        const int pos = m0 + wm*64 + mi*16 + li;
        const int och = wn*32 + ni*16 + g*4;
        ushort4 hv, lv;
        #pragma unroll
        for (int r = 0; r < 4; ++r){
          const float v = acc[mi][ni][r];
          const unsigned short hb = f2bf(v);
          ((unsigned short*)&hv)[r] = hb;
          ((unsigned short*)&lv)[r] = f2bf(v - bf2f(hb));
        }
        const size_t off = (size_t)pos*64 + (och & 63);
        if (wn < 2){ *(ushort4*)&qh[off] = hv; *(ushort4*)&ql[off] = lv; }
        else       { *(ushort4*)&kh[off] = hv; *(ushort4*)&kl[off] = lv; }
      }
  }

  // ---- half 1: v (normal: D[m=pos][n=ch]) ----
  {
    f32x4 acc[4][2] = {};
    #pragma unroll
    for (int ks = 0; ks < 4; ++ks){
      const int col = ks*32 + g*8;
      s16x8 ah[4], al[4];
      #pragma unroll
      for (int mi = 0; mi < 4; ++mi){
        const int idx = swzi(wm*64 + mi*16 + li, col, 128);
        ah[mi] = *(const s16x8*)&xh[idx];
        al[mi] = *(const s16x8*)&xl[idx];
      }
      #pragma unroll
      for (int ni = 0; ni < 2; ++ni){
        const size_t boff = (size_t)(128 + wn*32 + ni*16 + li)*128 + col;
        const s16x8 bh = *(const s16x8*)(wtH + boff);
        const s16x8 bl = *(const s16x8*)(wtL + boff);
        #pragma unroll
        for (int mi = 0; mi < 4; ++mi){
          acc[mi][ni] = MFMA_BF16(ah[mi], bh, acc[mi][ni]);
          acc[mi][ni] = MFMA_BF16(ah[mi], bl, acc[mi][ni]);
          acc[mi][ni] = MFMA_BF16(al[mi], bh, acc[mi][ni]);
        }
      }
    }
    #pragma unroll
    for (int mi = 0; mi < 4; ++mi)
      #pragma unroll
      for (int ni = 0; ni < 2; ++ni){
        const int growb = m0 + wm*64 + mi*16 + g*4;   // 4 consecutive pos
        const int ch = wn*32 + ni*16 + li;
        const int head = growb >> 9, posb = growb & 511;
        ushort4 pv;
        #pragma unroll
        for (int r = 0; r < 4; ++r)
          ((unsigned short*)&pv)[r] = f2bf(acc[mi][ni][r]);
        *(ushort4*)&vT[((size_t)head << 16) + ch*512 + posb] = pv;
      }
  }
}

// ---------------- kernel 2: per-head attention, K/V persistent in regs ------
// 512 threads = 8 waves; block = ONE head; wave owns 64-k slice (K) and
// 16-ch slice (V), both loaded ONCE into registers; loop over 8 q-tiles.
__global__ __launch_bounds__(512,2) void k2_attn(
    const unsigned short* __restrict__ qh, const unsigned short* __restrict__ ql,
    const unsigned short* __restrict__ kh, const unsigned short* __restrict__ kl,
    const unsigned short* __restrict__ vT, const float* __restrict__ x,
    float* __restrict__ y, float* __restrict__ wout){
  __shared__ unsigned short wlds[32768];          // 64 KB (swizzled bf16 w, 64x512)
  __shared__ float redm[512], reds[512];          // 64 rows x 8 waves

  const int t = threadIdx.x;
  const int lane = t & 63, wid = t >> 6;
  const int li = lane & 15, g = lane >> 4;
  const int head = blockIdx.x;
  const size_t hbase = (size_t)head * 512;
  const int kbase = wid * 64;                     // wave's k-slice

  // persistent K fragments (A-operand of swapped QK^T): 16 x s16x8 = 64 VGPR
  s16x8 kregh[2][4], kregl[2][4];
  #pragma unroll
  for (int ks = 0; ks < 2; ++ks)
    #pragma unroll
    for (int ni = 0; ni < 4; ++ni){
      const size_t boff = (hbase + kbase + ni*16 + li)*64 + ks*32 + g*8;
      kregh[ks][ni] = *(const s16x8*)(kh + boff);
      kregl[ks][ni] = *(const s16x8*)(kl + boff);
    }
  // persistent V fragments (A-operand of swapped PV): 16 x s16x8 = 64 VGPR
  s16x8 vreg[16];
  {
    const unsigned short* vhead = vT + ((size_t)head << 16) + (size_t)(wid*16 + li)*512;
    #pragma unroll
    for (int kt = 0; kt < 16; ++kt)
      vreg[kt] = *(const s16x8*)&vhead[kt*32 + g*8];
  }

  for (int qt = 0; qt < 8; ++qt){
    const int q0 = qt * 64;

    // Phase B: scores, swapped: A=K-reg, B=Q-frag, D[kcol][qrow]
    f32x4 acc[4][4] = {};                       // [qj][ni]
    #pragma unroll
    for (int ks = 0; ks < 2; ++ks){
      const int col = ks*32 + g*8;
      s16x8 qbh[4], qbl[4];
      #pragma unroll
      for (int qj = 0; qj < 4; ++qj){
        const size_t aoff = (hbase + q0 + qj*16 + li)*64 + col;
        qbh[qj] = *(const s16x8*)(qh + aoff);
        qbl[qj] = *(const s16x8*)(ql + aoff);
      }
      #pragma unroll
      for (int ni = 0; ni < 4; ++ni)
        #pragma unroll
        for (int qj = 0; qj < 4; ++qj){
          acc[qj][ni] = MFMA_BF16(kregh[ks][ni], qbh[qj], acc[qj][ni]);
          acc[qj][ni] = MFMA_BF16(kregl[ks][ni], qbh[qj], acc[qj][ni]);
          acc[qj][ni] = MFMA_BF16(kregh[ks][ni], qbl[qj], acc[qj][ni]);
        }
    }

    // Phase C: softmax. Lane's q-row = qj*16+li. exp computed ONCE.
    float fsc[4];
    #pragma unroll
    for (int qj = 0; qj < 4; ++qj){
      float m = acc[qj][0][0];
      #pragma unroll
      for (int ni = 0; ni < 4; ++ni)
        #pragma unroll
        for (int r = 0; r < 4; ++r) m = fmaxf(m, acc[qj][ni][r]);
      m = fmaxf(m, __shfl_xor(m, 16));
      m = fmaxf(m, __shfl_xor(m, 32));
      float s = 0.f;
      #pragma unroll
      for (int ni = 0; ni < 4; ++ni)
        #pragma unroll
        for (int r = 0; r < 4; ++r){
          const float e = __expf(acc[qj][ni][r] - m);
          acc[qj][ni][r] = e;
          s += e;
        }
      s += __shfl_xor(s, 16);
      s += __shfl_xor(s, 32);
      if (g == 0){
        redm[(qj*16 + li)*8 + wid] = m;
        reds[(qj*16 + li)*8 + wid] = s;
      }
      fsc[qj] = m;                    // hold wave-local max
    }
    __syncthreads();
    #pragma unroll
    for (int qj = 0; qj < 4; ++qj){
      const int row = qj*16 + li;
      const f32x4 m0v = *(const f32x4*)&redm[row*8];
      const f32x4 m1v = *(const f32x4*)&redm[row*8 + 4];
      const f32x4 s0v = *(const f32x4*)&reds[row*8];
      const f32x4 s1v = *(const f32x4*)&reds[row*8 + 4];
      float M = fmaxf(fmaxf(fmaxf(m0v[0], m0v[1]), fmaxf(m0v[2], m0v[3])),
                      fmaxf(fmaxf(m1v[0], m1v[1]), fmaxf(m1v[2], m1v[3])));
      float S = s0v[0]*__expf(m0v[0] - M) + s0v[1]*__expf(m0v[1] - M)
              + s0v[2]*__expf(m0v[2] - M) + s0v[3]*__expf(m0v[3] - M)
              + s1v[0]*__expf(m1v[0] - M) + s1v[1]*__expf(m1v[1] - M)
              + s1v[2]*__expf(m1v[2] - M) + s1v[3]*__expf(m1v[3] - M);
      fsc[qj] = __expf(fsc[qj] - M) / S;   // global rescale for this lane's row
    }

    // Phase D: w = acc * fsc; float4 plain stores + LDS stash
    #pragma unroll
    for (int qj = 0; qj < 4; ++qj){
      const int row = qj*16 + li;
      float* wrow = wout + (hbase + q0 + row)*512;
      #pragma unroll
      for (int ni = 0; ni < 4; ++ni){
        const int col = kbase + ni*16 + g*4;
        f32x4 wv;
        ushort4 pv;
        #pragma unroll
        for (int r = 0; r < 4; ++r){
          const float v = acc[qj][ni][r] * fsc[qj];
          wv[r] = v;
          ((unsigned short*)&pv)[r] = f2bf(v);
        }
        *(f32x4*)&wrow[col] = wv;
        *(ushort4*)&wlds[swzi(row, col, 512)] = pv;
      }
    }
    __syncthreads();

    // Phase E: y = w.v, swapped: A=V-reg (ch rows), B=w-frag, D[ch][qrow]
    const int c0 = wid * 16;                    // wave's 16-ch slice
    f32x4 yacc[4] = {};                         // [mi] over 64 q-rows
    #pragma unroll
    for (int kt = 0; kt < 16; ++kt){
      const int kp0 = kt*32 + g*8;
      #pragma unroll
      for (int mi = 0; mi < 4; ++mi){
        const s16x8 aw = *(const s16x8*)&wlds[swzi(mi*16 + li, kp0, 512)];
        yacc[mi] = MFMA_BF16(vreg[kt], aw, yacc[mi]);
      }
    }

    // epilogue: lane: q-row = mi*16+li, 4 consecutive ch = c0+g*4
    #pragma unroll
    for (int mi = 0; mi < 4; ++mi){
      const int row = mi*16 + li;
      const size_t idx = (hbase + q0 + row)*128 + c0 + g*4;
      const f32x4 xv = __builtin_nontemporal_load((const f32x4*)&x[idx]);
      f32x4 ov;
      ov[0] = xv[0] + yacc[mi][0];
      ov[1] = xv[1] + yacc[mi][1];
      ov[2] = xv[2] + yacc[mi][2];
      ov[3] = xv[3] + yacc[mi][3];
      *(f32x4*)&y[idx] = ov;
    }
  }
}

extern "C" void kernel_launch(void* const* d_in, const int* in_sizes, int n_in,
                              void* d_out, int out_size, void* d_ws, size_t ws_size,
                              hipStream_t stream){
  (void)in_sizes; (void)n_in; (void)out_size; (void)ws_size;
  const float* x = (const float*)d_in[0];
  const float* W = (const float*)d_in[1];
  float* y    = (float*)d_out;                        // 33,554,432 f32
  float* wout = y + (size_t)33554432;                 // 134,217,728 f32

  char* ws = (char*)d_ws;
  unsigned short* qh  = (unsigned short*)(ws);                        // 32 MB
  unsigned short* ql  = (unsigned short*)(ws +  33554432ull);         // 32 MB
  unsigned short* kh  = (unsigned short*)(ws +  67108864ull);         // 32 MB
  unsigned short* kl  = (unsigned short*)(ws + 100663296ull);         // 32 MB
  unsigned short* vT  = (unsigned short*)(ws + 134217728ull);         // 64 MB
  unsigned short* wtH = (unsigned short*)(ws + 201326592ull);         // 64 KB
  unsigned short* wtL = (unsigned short*)(ws + 201392128ull);         // 64 KB

  hipLaunchKernelGGL(k0_wt,   dim3(256),  dim3(128), 0, stream, W, wtH, wtL);
  hipLaunchKernelGGL(k1_qkv,  dim3(2048), dim3(512), 0, stream, x, wtH, wtL,
                     qh, ql, kh, kl, vT);
  hipLaunchKernelGGL(k2_attn, dim3(512),  dim3(512), 0, stream,
                     qh, ql, kh, kl, vT, x, y, wout);
}

// Round 10
// 745.497 us; speedup vs baseline: 1.0002x; 1.0002x over previous
//
#include <hip/hip_runtime.h>
#include <hip/hip_bf16.h>

typedef short s16x8 __attribute__((ext_vector_type(8)));
typedef float f32x4 __attribute__((ext_vector_type(4)));

#define MFMA_BF16(a,b,c) __builtin_amdgcn_mfma_f32_16x16x32_bf16((a),(b),(c),0,0,0)

static __device__ __forceinline__ unsigned short f2bf(float f){
  unsigned u = __builtin_bit_cast(unsigned, f);
  u += 0x7fffu + ((u >> 16) & 1u);          // RNE
  return (unsigned short)(u >> 16);
}
static __device__ __forceinline__ float bf2f(unsigned short h){
  unsigned u = ((unsigned)h) << 16;
  return __builtin_bit_cast(float, u);
}
// XOR swizzle on 16B chunks. lw = row width in shorts.
static __device__ __forceinline__ int swzi(int row, int col, int lw){
  const int chunk = (col >> 3) ^ ((row ^ (row >> 3)) & 7);
  return row*lw + (chunk << 3) + (col & 7);
}

// ---------------- kernel 0: W transpose + hi/lo split ------------------------
__global__ __launch_bounds__(128) void k0_wt(const float* __restrict__ W,
                                             unsigned short* __restrict__ wtH,
                                             unsigned short* __restrict__ wtL){
  const int n = blockIdx.x;       // 0..255 output col
  const int c = threadIdx.x;      // 0..127 input ch
  const float v = W[(size_t)c*256 + n];
  const unsigned short h = f2bf(v);
  wtH[n*128 + c] = h;
  wtL[n*128 + c] = f2bf(v - bf2f(h));
}

// ---------------- kernel 1: qkv = x @ W (split-bf16) -------------------------
__global__ __launch_bounds__(512,2) void k1_qkv(const float* __restrict__ x,
    const unsigned short* __restrict__ wtH, const unsigned short* __restrict__ wtL,
    unsigned short* __restrict__ qh, unsigned short* __restrict__ ql,
    unsigned short* __restrict__ kh, unsigned short* __restrict__ kl,
    unsigned short* __restrict__ vT){
  __shared__ unsigned short xh[16384], xl[16384];   // 64 KB
  const int t = threadIdx.x;
  const int lane = t & 63, wid = t >> 6;
  const int li = lane & 15, g = lane >> 4;
  const int m0 = blockIdx.x * 128;
  const int wm = wid >> 2, wn = wid & 3;

  // stage x tile (128 rows x 128 ch), split hi/lo, swizzled
  {
    const int row = t >> 2, cb = (t & 3) * 32;
    const float* src = x + (size_t)(m0 + row)*128 + cb;
    #pragma unroll
    for (int gg = 0; gg < 4; ++gg){
      const float4 v0 = ((const float4*)src)[2*gg];
      const float4 v1 = ((const float4*)src)[2*gg + 1];
      const float vv[8] = {v0.x,v0.y,v0.z,v0.w,v1.x,v1.y,v1.z,v1.w};
      s16x8 h, l;
      #pragma unroll
      for (int j = 0; j < 8; ++j){
        const unsigned short hb = f2bf(vv[j]);
        h[j] = (short)hb;
        l[j] = (short)f2bf(vv[j] - bf2f(hb));
      }
      const int idx = swzi(row, cb + 8*gg, 128);
      *(s16x8*)&xh[idx] = h;
      *(s16x8*)&xl[idx] = l;
    }
  }
  __syncthreads();

  // ---- half 0: q,k (operand-swapped: D[m=outch][n=pos]) ----
  {
    f32x4 acc[4][2] = {};
    #pragma unroll
    for (int ks = 0; ks < 4; ++ks){
      const int col = ks*32 + g*8;
      s16x8 ah[4], al[4];
      #pragma unroll
      for (int mi = 0; mi < 4; ++mi){
        const int idx = swzi(wm*64 + mi*16 + li, col, 128);
        ah[mi] = *(const s16x8*)&xh[idx];
        al[mi] = *(const s16x8*)&xl[idx];
      }
      #pragma unroll
      for (int ni = 0; ni < 2; ++ni){
        const size_t boff = (size_t)(wn*32 + ni*16 + li)*128 + col;
        const s16x8 bh = *(const s16x8*)(wtH + boff);
        const s16x8 bl = *(const s16x8*)(wtL + boff);
        #pragma unroll
        for (int mi = 0; mi < 4; ++mi){
          acc[mi][ni] = MFMA_BF16(bh, ah[mi], acc[mi][ni]);   // A=W, B=x
          acc[mi][ni] = MFMA_BF16(bh, al[mi], acc[mi][ni]);
          acc[mi][ni] = MFMA_BF16(bl, ah[mi], acc[mi][ni]);
        }
      }
    }
    #pragma unroll
    for (int mi = 0; mi < 4; ++mi)
      #pragma unroll
      for (int ni = 0; ni < 2; ++ni){
        const int pos = m0 + wm*64 + mi*16 + li;
        const int och = wn*32 + ni*16 + g*4;
        ushort4 hv, lv;
        #pragma unroll
        for (int r = 0; r < 4; ++r){
          const float v = acc[mi][ni][r];
          const unsigned short hb = f2bf(v);
          ((unsigned short*)&hv)[r] = hb;
          ((unsigned short*)&lv)[r] = f2bf(v - bf2f(hb));
        }
        const size_t off = (size_t)pos*64 + (och & 63);
        if (wn < 2){ *(ushort4*)&qh[off] = hv; *(ushort4*)&ql[off] = lv; }
        else       { *(ushort4*)&kh[off] = hv; *(ushort4*)&kl[off] = lv; }
      }
  }

  // ---- half 1: v (normal: D[m=pos][n=ch]) ----
  {
    f32x4 acc[4][2] = {};
    #pragma unroll
    for (int ks = 0; ks < 4; ++ks){
      const int col = ks*32 + g*8;
      s16x8 ah[4], al[4];
      #pragma unroll
      for (int mi = 0; mi < 4; ++mi){
        const int idx = swzi(wm*64 + mi*16 + li, col, 128);
        ah[mi] = *(const s16x8*)&xh[idx];
        al[mi] = *(const s16x8*)&xl[idx];
      }
      #pragma unroll
      for (int ni = 0; ni < 2; ++ni){
        const size_t boff = (size_t)(128 + wn*32 + ni*16 + li)*128 + col;
        const s16x8 bh = *(const s16x8*)(wtH + boff);
        const s16x8 bl = *(const s16x8*)(wtL + boff);
        #pragma unroll
        for (int mi = 0; mi < 4; ++mi){
          acc[mi][ni] = MFMA_BF16(ah[mi], bh, acc[mi][ni]);
          acc[mi][ni] = MFMA_BF16(ah[mi], bl, acc[mi][ni]);
          acc[mi][ni] = MFMA_BF16(al[mi], bh, acc[mi][ni]);
        }
      }
    }
    #pragma unroll
    for (int mi = 0; mi < 4; ++mi)
      #pragma unroll
      for (int ni = 0; ni < 2; ++ni){
        const int growb = m0 + wm*64 + mi*16 + g*4;   // 4 consecutive pos
        const int ch = wn*32 + ni*16 + li;
        const int head = growb >> 9, posb = growb & 511;
        ushort4 pv;
        #pragma unroll
        for (int r = 0; r < 4; ++r)
          ((unsigned short*)&pv)[r] = f2bf(acc[mi][ni][r]);
        *(ushort4*)&vT[((size_t)head << 16) + ch*512 + posb] = pv;
      }
  }
}

// ---------------- kernel 2: per-head attention, K/V persistent in regs ------
// 512 threads = 8 waves; block = ONE head; wave owns 64-k slice (K) and
// 16-ch slice (V), both loaded ONCE into registers; loop over 8 q-tiles.
// __launch_bounds__(512,1): 2nd arg is minBlocksPerMP -> (512,2) capped VGPRs
// at 128 and spilled ~116/thread (R9). (512,1) caps at 256; need ~244.
__global__ __launch_bounds__(512,1) void k2_attn(
    const unsigned short* __restrict__ qh, const unsigned short* __restrict__ ql,
    const unsigned short* __restrict__ kh, const unsigned short* __restrict__ kl,
    const unsigned short* __restrict__ vT, const float* __restrict__ x,
    float* __restrict__ y, float* __restrict__ wout){
  __shared__ unsigned short wlds[32768];          // 64 KB (swizzled bf16 w, 64x512)
  __shared__ float redm[512], reds[512];          // 64 rows x 8 waves

  const int t = threadIdx.x;
  const int lane = t & 63, wid = t >> 6;
  const int li = lane & 15, g = lane >> 4;
  const int head = blockIdx.x;
  const size_t hbase = (size_t)head * 512;
  const int kbase = wid * 64;                     // wave's k-slice

  // persistent K fragments (A-operand of swapped QK^T): 16 x s16x8 = 64 VGPR
  s16x8 kregh[2][4], kregl[2][4];
  #pragma unroll
  for (int ks = 0; ks < 2; ++ks)
    #pragma unroll
    for (int ni = 0; ni < 4; ++ni){
      const size_t boff = (hbase + kbase + ni*16 + li)*64 + ks*32 + g*8;
      kregh[ks][ni] = *(const s16x8*)(kh + boff);
      kregl[ks][ni] = *(const s16x8*)(kl + boff);
    }
  // persistent V fragments (A-operand of swapped PV): 16 x s16x8 = 64 VGPR
  s16x8 vreg[16];
  {
    const unsigned short* vhead = vT + ((size_t)head << 16) + (size_t)(wid*16 + li)*512;
    #pragma unroll
    for (int kt = 0; kt < 16; ++kt)
      vreg[kt] = *(const s16x8*)&vhead[kt*32 + g*8];
  }

  for (int qt = 0; qt < 8; ++qt){
    const int q0 = qt * 64;

    // Phase B: scores, swapped: A=K-reg, B=Q-frag, D[kcol][qrow]
    f32x4 acc[4][4] = {};                       // [qj][ni]
    #pragma unroll
    for (int ks = 0; ks < 2; ++ks){
      const int col = ks*32 + g*8;
      s16x8 qbh[4], qbl[4];
      #pragma unroll
      for (int qj = 0; qj < 4; ++qj){
        const size_t aoff = (hbase + q0 + qj*16 + li)*64 + col;
        qbh[qj] = *(const s16x8*)(qh + aoff);
        qbl[qj] = *(const s16x8*)(ql + aoff);
      }
      #pragma unroll
      for (int ni = 0; ni < 4; ++ni)
        #pragma unroll
        for (int qj = 0; qj < 4; ++qj){
          acc[qj][ni] = MFMA_BF16(kregh[ks][ni], qbh[qj], acc[qj][ni]);
          acc[qj][ni] = MFMA_BF16(kregl[ks][ni], qbh[qj], acc[qj][ni]);
          acc[qj][ni] = MFMA_BF16(kregh[ks][ni], qbl[qj], acc[qj][ni]);
        }
    }

    // Phase C: softmax. Lane's q-row = qj*16+li. exp computed ONCE.
    float fsc[4];
    #pragma unroll
    for (int qj = 0; qj < 4; ++qj){
      float m = acc[qj][0][0];
      #pragma unroll
      for (int ni = 0; ni < 4; ++ni)
        #pragma unroll
        for (int r = 0; r < 4; ++r) m = fmaxf(m, acc[qj][ni][r]);
      m = fmaxf(m, __shfl_xor(m, 16));
      m = fmaxf(m, __shfl_xor(m, 32));
      float s = 0.f;
      #pragma unroll
      for (int ni = 0; ni < 4; ++ni)
        #pragma unroll
        for (int r = 0; r < 4; ++r){
          const float e = __expf(acc[qj][ni][r] - m);
          acc[qj][ni][r] = e;
          s += e;
        }
      s += __shfl_xor(s, 16);
      s += __shfl_xor(s, 32);
      if (g == 0){
        redm[(qj*16 + li)*8 + wid] = m;
        reds[(qj*16 + li)*8 + wid] = s;
      }
      fsc[qj] = m;                    // hold wave-local max
    }
    __syncthreads();
    #pragma unroll
    for (int qj = 0; qj < 4; ++qj){
      const int row = qj*16 + li;
      const f32x4 m0v = *(const f32x4*)&redm[row*8];
      const f32x4 m1v = *(const f32x4*)&redm[row*8 + 4];
      const f32x4 s0v = *(const f32x4*)&reds[row*8];
      const f32x4 s1v = *(const f32x4*)&reds[row*8 + 4];
      float M = fmaxf(fmaxf(fmaxf(m0v[0], m0v[1]), fmaxf(m0v[2], m0v[3])),
                      fmaxf(fmaxf(m1v[0], m1v[1]), fmaxf(m1v[2], m1v[3])));
      float S = s0v[0]*__expf(m0v[0] - M) + s0v[1]*__expf(m0v[1] - M)
              + s0v[2]*__expf(m0v[2] - M) + s0v[3]*__expf(m0v[3] - M)
              + s1v[0]*__expf(m1v[0] - M) + s1v[1]*__expf(m1v[1] - M)
              + s1v[2]*__expf(m1v[2] - M) + s1v[3]*__expf(m1v[3] - M);
      fsc[qj] = __expf(fsc[qj] - M) / S;   // global rescale for this lane's row
    }

    // Phase D: w = acc * fsc; float4 plain stores + LDS stash
    #pragma unroll
    for (int qj = 0; qj < 4; ++qj){
      const int row = qj*16 + li;
      float* wrow = wout + (hbase + q0 + row)*512;
      #pragma unroll
      for (int ni = 0; ni < 4; ++ni){
        const int col = kbase + ni*16 + g*4;
        f32x4 wv;
        ushort4 pv;
        #pragma unroll
        for (int r = 0; r < 4; ++r){
          const float v = acc[qj][ni][r] * fsc[qj];
          wv[r] = v;
          ((unsigned short*)&pv)[r] = f2bf(v);
        }
        *(f32x4*)&wrow[col] = wv;
        *(ushort4*)&wlds[swzi(row, col, 512)] = pv;
      }
    }
    __syncthreads();

    // Phase E: y = w.v, swapped: A=V-reg (ch rows), B=w-frag, D[ch][qrow]
    const int c0 = wid * 16;                    // wave's 16-ch slice
    f32x4 yacc[4] = {};                         // [mi] over 64 q-rows
    #pragma unroll
    for (int kt = 0; kt < 16; ++kt){
      const int kp0 = kt*32 + g*8;
      #pragma unroll
      for (int mi = 0; mi < 4; ++mi){
        const s16x8 aw = *(const s16x8*)&wlds[swzi(mi*16 + li, kp0, 512)];
        yacc[mi] = MFMA_BF16(vreg[kt], aw, yacc[mi]);
      }
    }

    // epilogue: lane: q-row = mi*16+li, 4 consecutive ch = c0+g*4
    #pragma unroll
    for (int mi = 0; mi < 4; ++mi){
      const int row = mi*16 + li;
      const size_t idx = (hbase + q0 + row)*128 + c0 + g*4;
      const f32x4 xv = __builtin_nontemporal_load((const f32x4*)&x[idx]);
      f32x4 ov;
      ov[0] = xv[0] + yacc[mi][0];
      ov[1] = xv[1] + yacc[mi][1];
      ov[2] = xv[2] + yacc[mi][2];
      ov[3] = xv[3] + yacc[mi][3];
      *(f32x4*)&y[idx] = ov;
    }
  }
}

extern "C" void kernel_launch(void* const* d_in, const int* in_sizes, int n_in,
                              void* d_out, int out_size, void* d_ws, size_t ws_size,
                              hipStream_t stream){
  (void)in_sizes; (void)n_in; (void)out_size; (void)ws_size;
  const float* x = (const float*)d_in[0];
  const float* W = (const float*)d_in[1];
  float* y    = (float*)d_out;                        // 33,554,432 f32
  float* wout = y + (size_t)33554432;                 // 134,217,728 f32

  char* ws = (char*)d_ws;
  unsigned short* qh  = (unsigned short*)(ws);                        // 32 MB
  unsigned short* ql  = (unsigned short*)(ws +  33554432ull);         // 32 MB
  unsigned short* kh  = (unsigned short*)(ws +  67108864ull);         // 32 MB
  unsigned short* kl  = (unsigned short*)(ws + 100663296ull);         // 32 MB
  unsigned short* vT  = (unsigned short*)(ws + 134217728ull);         // 64 MB
  unsigned short* wtH = (unsigned short*)(ws + 201326592ull);         // 64 KB
  unsigned short* wtL = (unsigned short*)(ws + 201392128ull);         // 64 KB

  hipLaunchKernelGGL(k0_wt,   dim3(256),  dim3(128), 0, stream, W, wtH, wtL);
  hipLaunchKernelGGL(k1_qkv,  dim3(2048), dim3(512), 0, stream, x, wtH, wtL,
                     qh, ql, kh, kl, vT);
  hipLaunchKernelGGL(k2_attn, dim3(512),  dim3(512), 0, stream,
                     qh, ql, kh, kl, vT, x, y, wout);
}

// Round 11
// 488.688 us; speedup vs baseline: 1.5258x; 1.5255x over previous
//
#include <hip/hip_runtime.h>
#include <hip/hip_bf16.h>

typedef short s16x8 __attribute__((ext_vector_type(8)));
typedef float f32x4 __attribute__((ext_vector_type(4)));

#define MFMA_BF16(a,b,c) __builtin_amdgcn_mfma_f32_16x16x32_bf16((a),(b),(c),0,0,0)

static __device__ __forceinline__ unsigned short f2bf(float f){
  unsigned u = __builtin_bit_cast(unsigned, f);
  u += 0x7fffu + ((u >> 16) & 1u);          // RNE
  return (unsigned short)(u >> 16);
}
static __device__ __forceinline__ float bf2f(unsigned short h){
  unsigned u = ((unsigned)h) << 16;
  return __builtin_bit_cast(float, u);
}
// XOR swizzle on 16B chunks. lw = row width in shorts.
static __device__ __forceinline__ int swzi(int row, int col, int lw){
  const int chunk = (col >> 3) ^ ((row ^ (row >> 3)) & 7);
  return row*lw + (chunk << 3) + (col & 7);
}

// ---------------- kernel 0: W transpose + hi/lo split ------------------------
__global__ __launch_bounds__(128) void k0_wt(const float* __restrict__ W,
                                             unsigned short* __restrict__ wtH,
                                             unsigned short* __restrict__ wtL){
  const int n = blockIdx.x;       // 0..255 output col
  const int c = threadIdx.x;      // 0..127 input ch
  const float v = W[(size_t)c*256 + n];
  const unsigned short h = f2bf(v);
  wtH[n*128 + c] = h;
  wtL[n*128 + c] = f2bf(v - bf2f(h));
}

// ---------------- kernel 1: qkv = x @ W (split-bf16) -------------------------
__global__ __launch_bounds__(512,2) void k1_qkv(const float* __restrict__ x,
    const unsigned short* __restrict__ wtH, const unsigned short* __restrict__ wtL,
    unsigned short* __restrict__ qh, unsigned short* __restrict__ ql,
    unsigned short* __restrict__ kh, unsigned short* __restrict__ kl,
    unsigned short* __restrict__ vT){
  __shared__ unsigned short xh[16384], xl[16384];   // 64 KB
  const int t = threadIdx.x;
  const int lane = t & 63, wid = t >> 6;
  const int li = lane & 15, g = lane >> 4;
  const int m0 = blockIdx.x * 128;
  const int wm = wid >> 2, wn = wid & 3;

  // stage x tile (128 rows x 128 ch), split hi/lo, swizzled
  {
    const int row = t >> 2, cb = (t & 3) * 32;
    const float* src = x + (size_t)(m0 + row)*128 + cb;
    #pragma unroll
    for (int gg = 0; gg < 4; ++gg){
      const float4 v0 = ((const float4*)src)[2*gg];
      const float4 v1 = ((const float4*)src)[2*gg + 1];
      const float vv[8] = {v0.x,v0.y,v0.z,v0.w,v1.x,v1.y,v1.z,v1.w};
      s16x8 h, l;
      #pragma unroll
      for (int j = 0; j < 8; ++j){
        const unsigned short hb = f2bf(vv[j]);
        h[j] = (short)hb;
        l[j] = (short)f2bf(vv[j] - bf2f(hb));
      }
      const int idx = swzi(row, cb + 8*gg, 128);
      *(s16x8*)&xh[idx] = h;
      *(s16x8*)&xl[idx] = l;
    }
  }
  __syncthreads();

  // ---- half 0: q,k (operand-swapped: D[m=outch][n=pos]) ----
  {
    f32x4 acc[4][2] = {};
    #pragma unroll
    for (int ks = 0; ks < 4; ++ks){
      const int col = ks*32 + g*8;
      s16x8 ah[4], al[4];
      #pragma unroll
      for (int mi = 0; mi < 4; ++mi){
        const int idx = swzi(wm*64 + mi*16 + li, col, 128);
        ah[mi] = *(const s16x8*)&xh[idx];
        al[mi] = *(const s16x8*)&xl[idx];
      }
      #pragma unroll
      for (int ni = 0; ni < 2; ++ni){
        const size_t boff = (size_t)(wn*32 + ni*16 + li)*128 + col;
        const s16x8 bh = *(const s16x8*)(wtH + boff);
        const s16x8 bl = *(const s16x8*)(wtL + boff);
        #pragma unroll
        for (int mi = 0; mi < 4; ++mi){
          acc[mi][ni] = MFMA_BF16(bh, ah[mi], acc[mi][ni]);   // A=W, B=x
          acc[mi][ni] = MFMA_BF16(bh, al[mi], acc[mi][ni]);
          acc[mi][ni] = MFMA_BF16(bl, ah[mi], acc[mi][ni]);
        }
      }
    }
    #pragma unroll
    for (int mi = 0; mi < 4; ++mi)
      #pragma unroll
      for (int ni = 0; ni < 2; ++ni){
        const int pos = m0 + wm*64 + mi*16 + li;
        const int och = wn*32 + ni*16 + g*4;
        ushort4 hv, lv;
        #pragma unroll
        for (int r = 0; r < 4; ++r){
          const float v = acc[mi][ni][r];
          const unsigned short hb = f2bf(v);
          ((unsigned short*)&hv)[r] = hb;
          ((unsigned short*)&lv)[r] = f2bf(v - bf2f(hb));
        }
        const size_t off = (size_t)pos*64 + (och & 63);
        if (wn < 2){ *(ushort4*)&qh[off] = hv; *(ushort4*)&ql[off] = lv; }
        else       { *(ushort4*)&kh[off] = hv; *(ushort4*)&kl[off] = lv; }
      }
  }

  // ---- half 1: v (normal: D[m=pos][n=ch]) ----
  {
    f32x4 acc[4][2] = {};
    #pragma unroll
    for (int ks = 0; ks < 4; ++ks){
      const int col = ks*32 + g*8;
      s16x8 ah[4], al[4];
      #pragma unroll
      for (int mi = 0; mi < 4; ++mi){
        const int idx = swzi(wm*64 + mi*16 + li, col, 128);
        ah[mi] = *(const s16x8*)&xh[idx];
        al[mi] = *(const s16x8*)&xl[idx];
      }
      #pragma unroll
      for (int ni = 0; ni < 2; ++ni){
        const size_t boff = (size_t)(128 + wn*32 + ni*16 + li)*128 + col;
        const s16x8 bh = *(const s16x8*)(wtH + boff);
        const s16x8 bl = *(const s16x8*)(wtL + boff);
        #pragma unroll
        for (int mi = 0; mi < 4; ++mi){
          acc[mi][ni] = MFMA_BF16(ah[mi], bh, acc[mi][ni]);
          acc[mi][ni] = MFMA_BF16(ah[mi], bl, acc[mi][ni]);
          acc[mi][ni] = MFMA_BF16(al[mi], bh, acc[mi][ni]);
        }
      }
    }
    #pragma unroll
    for (int mi = 0; mi < 4; ++mi)
      #pragma unroll
      for (int ni = 0; ni < 2; ++ni){
        const int growb = m0 + wm*64 + mi*16 + g*4;   // 4 consecutive pos
        const int ch = wn*32 + ni*16 + li;
        const int head = growb >> 9, posb = growb & 511;
        ushort4 pv;
        #pragma unroll
        for (int r = 0; r < 4; ++r)
          ((unsigned short*)&pv)[r] = f2bf(acc[mi][ni][r]);
        *(ushort4*)&vT[((size_t)head << 16) + ch*512 + posb] = pv;
      }
  }
}

// ---------------- kernel 2: scores -> softmax -> w out; y = x + w.v ---------
// 512 threads = 8 waves; block = 64 q rows; wave owns 64-k slice.
// QK^T operand-swapped: D[kcol][qrow]; PV operand-swapped: D[ch][qrow].
// Output stores are NT float4 (full 64B-sector coverage per instruction) to
// keep the 640MB write stream out of L2 (write-allocate thrash theory).
__global__ __launch_bounds__(512,2) void k2_attn(
    const unsigned short* __restrict__ qh, const unsigned short* __restrict__ ql,
    const unsigned short* __restrict__ kh, const unsigned short* __restrict__ kl,
    const unsigned short* __restrict__ vT, const float* __restrict__ x,
    float* __restrict__ y, float* __restrict__ wout){
  __shared__ unsigned short wlds[32768];          // 64 KB (swizzled bf16 w, 64x512)
  __shared__ float redm[512], reds[512];          // 64 rows x 8 waves

  const int t = threadIdx.x;
  const int lane = t & 63, wid = t >> 6;
  const int li = lane & 15, g = lane >> 4;
  const int bi = blockIdx.x;
  // XCD-grouped: 8 blocks of a head share an XCD (bi&7)
  const int head = (bi & 7) + 8 * (bi >> 6);
  const int qt = (bi >> 3) & 7;
  const size_t hbase = (size_t)head * 512;
  const int q0 = qt * 64;
  const int kbase = wid * 64;                     // wave's k-slice

  // Phase B: scores, swapped: A=K-frag, B=Q-frag, D[kcol][qrow]
  f32x4 acc[4][4] = {};                           // [qj][ni]
  #pragma unroll
  for (int ks = 0; ks < 2; ++ks){
    const int col = ks*32 + g*8;
    s16x8 qbh[4], qbl[4];
    #pragma unroll
    for (int qj = 0; qj < 4; ++qj){
      const size_t aoff = (hbase + q0 + qj*16 + li)*64 + col;
      qbh[qj] = *(const s16x8*)(qh + aoff);
      qbl[qj] = *(const s16x8*)(ql + aoff);
    }
    #pragma unroll
    for (int ni = 0; ni < 4; ++ni){
      const size_t boff = (hbase + kbase + ni*16 + li)*64 + col;
      const s16x8 ah = *(const s16x8*)(kh + boff);
      const s16x8 al = *(const s16x8*)(kl + boff);
      #pragma unroll
      for (int qj = 0; qj < 4; ++qj){
        acc[qj][ni] = MFMA_BF16(ah, qbh[qj], acc[qj][ni]);
        acc[qj][ni] = MFMA_BF16(al, qbh[qj], acc[qj][ni]);
        acc[qj][ni] = MFMA_BF16(ah, qbl[qj], acc[qj][ni]);
      }
    }
  }

  // Phase C: softmax. Lane's q-row = qj*16+li. exp computed ONCE.
  float fsc[4];
  #pragma unroll
  for (int qj = 0; qj < 4; ++qj){
    float m = acc[qj][0][0];
    #pragma unroll
    for (int ni = 0; ni < 4; ++ni)
      #pragma unroll
      for (int r = 0; r < 4; ++r) m = fmaxf(m, acc[qj][ni][r]);
    m = fmaxf(m, __shfl_xor(m, 16));
    m = fmaxf(m, __shfl_xor(m, 32));
    float s = 0.f;
    #pragma unroll
    for (int ni = 0; ni < 4; ++ni)
      #pragma unroll
      for (int r = 0; r < 4; ++r){
        const float e = __expf(acc[qj][ni][r] - m);
        acc[qj][ni][r] = e;
        s += e;
      }
    s += __shfl_xor(s, 16);
    s += __shfl_xor(s, 32);
    if (g == 0){
      redm[(qj*16 + li)*8 + wid] = m;
      reds[(qj*16 + li)*8 + wid] = s;
    }
    fsc[qj] = m;                    // hold wave-local max
  }
  __syncthreads();
  #pragma unroll
  for (int qj = 0; qj < 4; ++qj){
    const int row = qj*16 + li;
    const f32x4 m0v = *(const f32x4*)&redm[row*8];
    const f32x4 m1v = *(const f32x4*)&redm[row*8 + 4];
    const f32x4 s0v = *(const f32x4*)&reds[row*8];
    const f32x4 s1v = *(const f32x4*)&reds[row*8 + 4];
    float M = fmaxf(fmaxf(fmaxf(m0v[0], m0v[1]), fmaxf(m0v[2], m0v[3])),
                    fmaxf(fmaxf(m1v[0], m1v[1]), fmaxf(m1v[2], m1v[3])));
    float S = s0v[0]*__expf(m0v[0] - M) + s0v[1]*__expf(m0v[1] - M)
            + s0v[2]*__expf(m0v[2] - M) + s0v[3]*__expf(m0v[3] - M)
            + s1v[0]*__expf(m1v[0] - M) + s1v[1]*__expf(m1v[1] - M)
            + s1v[2]*__expf(m1v[2] - M) + s1v[3]*__expf(m1v[3] - M);
    fsc[qj] = __expf(fsc[qj] - M) / S;   // global rescale for this lane's row
  }

  // Phase D: w = acc * fsc; NT float4 stores (full 64B sectors) + LDS stash
  #pragma unroll
  for (int qj = 0; qj < 4; ++qj){
    const int row = qj*16 + li;
    float* wrow = wout + (hbase + q0 + row)*512;
    #pragma unroll
    for (int ni = 0; ni < 4; ++ni){
      const int col = kbase + ni*16 + g*4;
      f32x4 wv;
      ushort4 pv;
      #pragma unroll
      for (int r = 0; r < 4; ++r){
        const float v = acc[qj][ni][r] * fsc[qj];
        wv[r] = v;
        ((unsigned short*)&pv)[r] = f2bf(v);
      }
      __builtin_nontemporal_store(wv, (f32x4*)&wrow[col]);
      *(ushort4*)&wlds[swzi(row, col, 512)] = pv;
    }
  }
  __syncthreads();

  // Phase E: y = w.v, swapped: A=vT-frag (ch rows), B=w-frag, D[ch][qrow]
  const int c0 = wid * 16;                        // wave's 16-ch slice
  f32x4 yacc[4] = {};                             // [mi] over 64 q-rows
  const unsigned short* vhead = vT + ((size_t)head << 16) + (size_t)(c0 + li)*512;
  #pragma unroll
  for (int kt = 0; kt < 16; ++kt){
    const int kp0 = kt*32 + g*8;
    const s16x8 vb = *(const s16x8*)&vhead[kp0];
    #pragma unroll
    for (int mi = 0; mi < 4; ++mi){
      const s16x8 aw = *(const s16x8*)&wlds[swzi(mi*16 + li, kp0, 512)];
      yacc[mi] = MFMA_BF16(vb, aw, yacc[mi]);
    }
  }

  // epilogue: lane: q-row = mi*16+li, 4 consecutive ch = c0+g*4
  #pragma unroll
  for (int mi = 0; mi < 4; ++mi){
    const int row = mi*16 + li;
    const size_t idx = (hbase + q0 + row)*128 + c0 + g*4;
    const f32x4 xv = __builtin_nontemporal_load((const f32x4*)&x[idx]);
    f32x4 ov;
    ov[0] = xv[0] + yacc[mi][0];
    ov[1] = xv[1] + yacc[mi][1];
    ov[2] = xv[2] + yacc[mi][2];
    ov[3] = xv[3] + yacc[mi][3];
    __builtin_nontemporal_store(ov, (f32x4*)&y[idx]);
  }
}

extern "C" void kernel_launch(void* const* d_in, const int* in_sizes, int n_in,
                              void* d_out, int out_size, void* d_ws, size_t ws_size,
                              hipStream_t stream){
  (void)in_sizes; (void)n_in; (void)out_size; (void)ws_size;
  const float* x = (const float*)d_in[0];
  const float* W = (const float*)d_in[1];
  float* y    = (float*)d_out;                        // 33,554,432 f32
  float* wout = y + (size_t)33554432;                 // 134,217,728 f32

  char* ws = (char*)d_ws;
  unsigned short* qh  = (unsigned short*)(ws);                        // 32 MB
  unsigned short* ql  = (unsigned short*)(ws +  33554432ull);         // 32 MB
  unsigned short* kh  = (unsigned short*)(ws +  67108864ull);         // 32 MB
  unsigned short* kl  = (unsigned short*)(ws + 100663296ull);         // 32 MB
  unsigned short* vT  = (unsigned short*)(ws + 134217728ull);         // 64 MB
  unsigned short* wtH = (unsigned short*)(ws + 201326592ull);         // 64 KB
  unsigned short* wtL = (unsigned short*)(ws + 201392128ull);         // 64 KB

  hipLaunchKernelGGL(k0_wt,   dim3(256),  dim3(128), 0, stream, W, wtH, wtL);
  hipLaunchKernelGGL(k1_qkv,  dim3(2048), dim3(512), 0, stream, x, wtH, wtL,
                     qh, ql, kh, kl, vT);
  hipLaunchKernelGGL(k2_attn, dim3(4096), dim3(512), 0, stream,
                     qh, ql, kh, kl, vT, x, y, wout);
}